// Round 17
// baseline (403.430 us; speedup 1.0000x reference)
//
#include <hip/hip_runtime.h>

#ifndef __has_builtin
#define __has_builtin(x) 0
#endif

#define T_STEPS 512
#define BATCH   128
#define DIN     256
#define HID     256
#define WPLD    (DIN + HID)   // 512

// Volatile asm loads: results are NOT rematerializable (cheap insurance).
#define ASM_LOAD4(dst, ptr) \
    asm volatile("global_load_dwordx4 %0, %1, off" : "=v"(dst) : "v"(ptr))
#define ASM_LOAD1(dst, ptr) \
    asm volatile("global_load_dword %0, %1, off" : "=v"(dst) : "v"(ptr))

// Barrier WITHOUT vmcnt drain (verified R11/R12): waits only LDS ops.
#define STEP_BARRIER() do {                                   \
    asm volatile("s_waitcnt lgkmcnt(0)" ::: "memory");        \
    __builtin_amdgcn_s_barrier();                             \
    __builtin_amdgcn_sched_barrier(0);                        \
} while (0)

// ---------------- cross-lane helpers ----------------
// VALU-rate DPP: 0xB1=quad xor1, 0x4E=quad xor2, 0x124=row_ror:4,
// 0x128=row_ror:8 (rotation by half-row == xor8 value exchange).
template<int CTRL>
__device__ __forceinline__ float dppmov(float x) {
    return __int_as_float(__builtin_amdgcn_update_dpp(0, __float_as_int(x), CTRL, 0xF, 0xF, true));
}
template<int PAT>
__device__ __forceinline__ float swz(float x) {   // used only in projx
    return __int_as_float(__builtin_amdgcn_ds_swizzle(__float_as_int(x), PAT));
}
// permlane swaps: VALU-rate xor16/xor32 partner value (verified R8/R12).
__device__ __forceinline__ float lane_xor16(float v, int l) {
#if __has_builtin(__builtin_amdgcn_permlane16_swap)
    auto r = __builtin_amdgcn_permlane16_swap(__float_as_uint(v), __float_as_uint(v), false, false);
    return __uint_as_float((l & 16) ? r[0] : r[1]);
#else
    return swz<0x401F>(v);
#endif
}
__device__ __forceinline__ float lane_xor32(float v, int l) {
#if __has_builtin(__builtin_amdgcn_permlane32_swap)
    auto r = __builtin_amdgcn_permlane32_swap(__float_as_uint(v), __float_as_uint(v), false, false);
    return __uint_as_float((l & 32) ? r[0] : r[1]);
#else
    return __shfl_xor(v, 32);
#endif
}
__device__ __forceinline__ float rcp_f(float x) {
#if __has_builtin(__builtin_amdgcn_rcpf)
    return __builtin_amdgcn_rcpf(x);
#else
    return 1.0f / x;
#endif
}

// ---------------------------------------------------------------------------
// Kernel 1: px[b][t][q] = sum_d x[t,b,d]*Wp[q,d] + qp[q]   (unchanged, verified)
// ---------------------------------------------------------------------------
__global__ __launch_bounds__(256) void qlstm_projx(const float* __restrict__ x,
                                                   const float* __restrict__ Wp,
                                                   const float* __restrict__ qp,
                                                   float* __restrict__ px) {
    const int wave = threadIdx.x >> 6;
    const int lane = threadIdx.x & 63;
    const int row  = blockIdx.x * 4 + wave;       // row = t*BATCH + b

    const float4 xv = ((const float4*)(x + (size_t)row * DIN))[lane];
    float acc[8];
#pragma unroll
    for (int Q = 0; Q < 8; ++Q) {
        float4 w = ((const float4*)(Wp + Q * WPLD))[lane];
        acc[Q] = xv.x * w.x + xv.y * w.y + xv.z * w.z + xv.w * w.w;
    }
#pragma unroll
    for (int Q = 0; Q < 8; ++Q) {
        acc[Q] += dppmov<0xB1>(acc[Q]);
        acc[Q] += dppmov<0x4E>(acc[Q]);
        acc[Q] += swz<0x101F>(acc[Q]);
    }
    float p = acc[0];
#pragma unroll
    for (int j = 1; j < 8; ++j) p = ((lane & 7) == j) ? acc[j] : p;
    p += swz<0x201F>(p);
    p += swz<0x401F>(p);
    p += __shfl_xor(p, 32);
    if (lane < 8) {
        const int bb = row & (BATCH - 1);
        const int tt = row >> 7;
        px[(size_t)bb * (T_STEPS * 8) + tt * 8 + lane] = p + qp[lane];
    }
}

// ---------------------------------------------------------------------------
// Kernel 2: recurrence. ONE barrier + ONE LDS round-trip per step; all other
// cross-lane traffic is VALU-rate (DPP + permlane swaps).
// Thread (w,l) owns column cg=64w+l; h stays in a register.
// Phase A: 8 full-wave allreduce chains (xor1,xor2,ror4,ror8 DPP +
// permlane16/32) over the wave's own 64 columns; lanes 0-7 publish raw
// partials part[t&1][q][w]. Barrier. Phase B: 1 ds_read_b128 gathers the 4
// waves' partials for q=l>>3, +px, ONE cos/lane; all-VALU butterfly-collect
// (ror8 / permlane16 / permlane32) broadcasts the 8 C's; prefix/gates/LSTM
// verbatim R12. part[] double-buffered: barrier at t+1 separates phase-B
// reads of buffer t&1 from their overwrite at t+2.
// ---------------------------------------------------------------------------
__global__ __launch_bounds__(256, 1) void qlstm_seq(const float* __restrict__ hx,
                                                    const float* __restrict__ cx,
                                                    const float* __restrict__ Wp,
                                                    const float* __restrict__ Wg,
                                                    const float* __restrict__ bg,
                                                    const float* __restrict__ px,
                                                    float* __restrict__ out) {
    __shared__ float px_lds[(T_STEPS + 1) * 8];   // +8 pad for prefetch overrun
    __shared__ float part[2][8][4];               // [buf][q][wave] raw partials

    const int tid = threadIdx.x;
    const int w   = tid >> 6;     // wave id 0..3
    const int l   = tid & 63;     // lane
    const int b   = blockIdx.x;
    const int cg  = tid;          // this thread's column (owns h[cg], c[cg])
    const int qb  = l >> 3;       // phase-B q assignment

    // ---- weight loads (asm: non-rematerializable) ----
    float wph[8];                 // Wp[q][256+cg] — own column's proj weights
#pragma unroll
    for (int q = 0; q < 8; ++q) {
        const float* a = Wp + q * WPLD + DIN + cg;
        ASM_LOAD1(wph[q], a);
    }
    float4 WG0[4], WG1[4];        // Wg row (G*256+cg), floats 0..7
#pragma unroll
    for (int G = 0; G < 4; ++G) {
        const float* r = Wg + (size_t)(G * HID + cg) * 8;
        ASM_LOAD4(WG0[G], r);
        ASM_LOAD4(WG1[G], r + 4);
    }
    float bgc[4];                 // bg[G*256+cg]
#pragma unroll
    for (int G = 0; G < 4; ++G) {
        const float* a = bg + G * HID + cg;
        ASM_LOAD1(bgc[G], a);
    }

    // preload all px for this b (4096 floats = 1024 float4, 4 per thread)
    {
        const float4* pg = (const float4*)(px + (size_t)b * (T_STEPS * 8));
        float4* pl = (float4*)px_lds;
#pragma unroll
        for (int j = 0; j < 4; ++j) pl[j * 256 + tid] = pg[j * 256 + tid];
    }

    float hreg = hx[b * HID + cg];
    float c    = cx[b * HID + cg];

    asm volatile("s_waitcnt vmcnt(0)" ::: "memory");
    __builtin_amdgcn_sched_barrier(0);
    __syncthreads();   // px_lds ready (prologue only)

    float pxq = px_lds[qb];   // px[t=0][qb], prefetched

    float* outp = out + (size_t)b * HID + cg;

    for (int t = 0; t < T_STEPS; ++t) {
        // ---- phase A: 8 all-VALU full-wave allreduce chains (h in reg) ----
        float acc[8];
#pragma unroll
        for (int q = 0; q < 8; ++q) acc[q] = hreg * wph[q];
#pragma unroll
        for (int q = 0; q < 8; ++q) {
            float v = acc[q];
            v += dppmov<0xB1>(v);        // xor1   (DPP)
            v += dppmov<0x4E>(v);        // xor2   (DPP)
            v += dppmov<0x124>(v);       // ror4   (DPP rotation-reduce)
            v += dppmov<0x128>(v);       // ror8   (DPP rotation-reduce)
            v += lane_xor16(v, l);       // permlane16_swap (VALU)
            v += lane_xor32(v, l);       // permlane32_swap (VALU)
            acc[q] = v;
        }
        // lanes 0-7 publish this wave's raw partial for q=l
        float p = acc[0];
#pragma unroll
        for (int j = 1; j < 8; ++j) p = ((l & 7) == j) ? acc[j] : p;
        if (l < 8) part[t & 1][l][w] = p;

        STEP_BARRIER();   // the ONLY barrier per step

        // ---- phase B: gather partials, cos, all-VALU collect, gates, LSTM ----
        const float4 f4 = *(const float4*)&part[t & 1][qb][0];
        const float S  = ((f4.x + f4.y) + (f4.z + f4.w)) + pxq;
        const float cw = __cosf(S);          // ONE cos per lane (its q=qb)

        pxq = px_lds[(t + 1) * 8 + qb];      // prefetch next px (off-path)

        // butterfly-collect, all VALU: ror8 == xor8 value exchange in row16;
        // permlane16/32 for xor16/xor32. Select pattern verbatim from R2.
        float o8 = dppmov<0x128>(cw);
        float x0 = (l & 8) ? o8 : cw;
        float x1 = (l & 8) ? cw : o8;
        float y0 = lane_xor16(x0, l), y1 = lane_xor16(x1, l);
        float b0 = (l & 16) ? y0 : x0;
        float b1 = (l & 16) ? y1 : x1;
        float b2 = (l & 16) ? x0 : y0;
        float b3 = (l & 16) ? x1 : y1;
        float z0 = lane_xor32(b0, l), z1 = lane_xor32(b1, l);
        float z2 = lane_xor32(b2, l), z3 = lane_xor32(b3, l);
        const float C0 = (l & 32) ? z0 : b0;
        const float C1 = (l & 32) ? z1 : b1;
        const float C2 = (l & 32) ? z2 : b2;
        const float C3 = (l & 32) ? z3 : b3;
        const float C4 = (l & 32) ? b0 : z0;
        const float C5 = (l & 32) ? b1 : z1;
        const float C6 = (l & 32) ? b2 : z2;
        const float C7 = (l & 32) ? b3 : z3;

        // prefix products: qo[0]=C1..C7, qo[k>=1]=C0..Ck
        const float d01 = C0 * C1, d23 = C2 * C3, d45 = C4 * C5, d67 = C6 * C7;
        float qo[8];
        qo[1] = d01;
        qo[2] = d01 * C2;
        qo[3] = d01 * d23;
        qo[4] = qo[3] * C4;
        qo[5] = qo[3] * d45;
        qo[6] = qo[5] * C6;
        qo[7] = qo[5] * d67;
        qo[0] = (C1 * d23) * (d45 * d67);

        // gates for this thread's single column (tree-structured, as R12)
        float gf, gi, gg, go;
        {
            float a0, a1;
            a0 = fmaf(WG0[0].x, qo[0], bgc[0]);  a0 = fmaf(WG0[0].y, qo[1], a0);
            a0 = fmaf(WG0[0].z, qo[2], a0);      a0 = fmaf(WG0[0].w, qo[3], a0);
            a1 = WG1[0].x * qo[4];               a1 = fmaf(WG1[0].y, qo[5], a1);
            a1 = fmaf(WG1[0].z, qo[6], a1);      a1 = fmaf(WG1[0].w, qo[7], a1);
            gf = a0 + a1;
            a0 = fmaf(WG0[1].x, qo[0], bgc[1]);  a0 = fmaf(WG0[1].y, qo[1], a0);
            a0 = fmaf(WG0[1].z, qo[2], a0);      a0 = fmaf(WG0[1].w, qo[3], a0);
            a1 = WG1[1].x * qo[4];               a1 = fmaf(WG1[1].y, qo[5], a1);
            a1 = fmaf(WG1[1].z, qo[6], a1);      a1 = fmaf(WG1[1].w, qo[7], a1);
            gi = a0 + a1;
            a0 = fmaf(WG0[2].x, qo[0], bgc[2]);  a0 = fmaf(WG0[2].y, qo[1], a0);
            a0 = fmaf(WG0[2].z, qo[2], a0);      a0 = fmaf(WG0[2].w, qo[3], a0);
            a1 = WG1[2].x * qo[4];               a1 = fmaf(WG1[2].y, qo[5], a1);
            a1 = fmaf(WG1[2].z, qo[6], a1);      a1 = fmaf(WG1[2].w, qo[7], a1);
            gg = a0 + a1;
            a0 = fmaf(WG0[3].x, qo[0], bgc[3]);  a0 = fmaf(WG0[3].y, qo[1], a0);
            a0 = fmaf(WG0[3].z, qo[2], a0);      a0 = fmaf(WG0[3].w, qo[3], a0);
            a1 = WG1[3].x * qo[4];               a1 = fmaf(WG1[3].y, qo[5], a1);
            a1 = fmaf(WG1[3].z, qo[6], a1);      a1 = fmaf(WG1[3].w, qo[7], a1);
            go = a0 + a1;
        }

        // LSTM pointwise, parallel form (inf-safe, no clamp) — as R12
        const float sf = rcp_f(1.f + __expf(-gf));
        const float si = rcp_f(1.f + __expf(-gi));
        const float so = rcp_f(1.f + __expf(-go));
        const float tg = 1.f - 2.f * rcp_f(__expf(2.f * gg) + 1.f);
        const float cn = fmaf(sf, c, si * tg);
        const float th = 1.f - 2.f * rcp_f(__expf(2.f * cn) + 1.f);
        const float h  = so * th;
        c = cn;

        *outp = h;                   // global store; not drained at barrier
        outp += BATCH * HID;

        hreg = h;                    // h stays in register — no LDS publish
    }

    const size_t base = (size_t)T_STEPS * BATCH * HID;
    out[base + b * HID + cg] = hreg;
    out[base + BATCH * HID + b * HID + cg] = c;
}

extern "C" void kernel_launch(void* const* d_in, const int* in_sizes, int n_in,
                              void* d_out, int out_size, void* d_ws, size_t ws_size,
                              hipStream_t stream) {
    const float* x   = (const float*)d_in[0];   // (512,128,256)
    const float* hx  = (const float*)d_in[1];   // (128,256)
    const float* cx  = (const float*)d_in[2];   // (128,256)
    const float* Wp  = (const float*)d_in[3];   // (8,512)
    const float* qp  = (const float*)d_in[4];   // (8,)
    const float* Wg  = (const float*)d_in[5];   // (1024,8)
    const float* bg  = (const float*)d_in[6];   // (1024,)
    float* out = (float*)d_out;
    float* px  = (float*)d_ws;                  // 128*512*8 floats = 2 MB

    qlstm_projx<<<(T_STEPS * BATCH) / 4, 256, 0, stream>>>(x, Wp, qp, px);
    qlstm_seq<<<BATCH, 256, 0, stream>>>(hx, cx, Wp, Wg, bg, px, out);
}

// Round 18
// 364.681 us; speedup vs baseline: 1.1063x; 1.1063x over previous
//
#include <hip/hip_runtime.h>

#ifndef __has_builtin
#define __has_builtin(x) 0
#endif

#define T_STEPS 512
#define BATCH   128
#define DIN     256
#define HID     256
#define WPLD    (DIN + HID)   // 512

typedef float v2f __attribute__((ext_vector_type(2)));

// Volatile asm loads: results are NOT rematerializable (cheap insurance).
#define ASM_LOAD4(dst, ptr) \
    asm volatile("global_load_dwordx4 %0, %1, off" : "=v"(dst) : "v"(ptr))
#define ASM_LOAD1(dst, ptr) \
    asm volatile("global_load_dword %0, %1, off" : "=v"(dst) : "v"(ptr))

// Barrier WITHOUT vmcnt drain (verified R11/R12): waits only LDS ops.
#define STEP_BARRIER() do {                                   \
    asm volatile("s_waitcnt lgkmcnt(0)" ::: "memory");        \
    __builtin_amdgcn_s_barrier();                             \
    __builtin_amdgcn_sched_barrier(0);                        \
} while (0)

// ---------------- cross-lane helpers (verified in passing runs) ----------------
template<int CTRL>
__device__ __forceinline__ float dppmov(float x) {
    // 0xB1=quad xor1, 0x4E=quad xor2, 0x124=row_ror:4, 0x128=row_ror:8
    return __int_as_float(__builtin_amdgcn_update_dpp(0, __float_as_int(x), CTRL, 0xF, 0xF, true));
}
template<int PAT>
__device__ __forceinline__ float swz(float x) {
    return __int_as_float(__builtin_amdgcn_ds_swizzle(__float_as_int(x), PAT));
}
__device__ __forceinline__ float lane_xor16(float v, int l) {
#if __has_builtin(__builtin_amdgcn_permlane16_swap)
    auto r = __builtin_amdgcn_permlane16_swap(__float_as_uint(v), __float_as_uint(v), false, false);
    return __uint_as_float((l & 16) ? r[0] : r[1]);
#else
    return swz<0x401F>(v);
#endif
}
__device__ __forceinline__ float lane_xor32(float v, int l) {
#if __has_builtin(__builtin_amdgcn_permlane32_swap)
    auto r = __builtin_amdgcn_permlane32_swap(__float_as_uint(v), __float_as_uint(v), false, false);
    return __uint_as_float((l & 32) ? r[0] : r[1]);
#else
    return __shfl_xor(v, 32);
#endif
}
__device__ __forceinline__ float rcp_f(float x) {
#if __has_builtin(__builtin_amdgcn_rcpf)
    return __builtin_amdgcn_rcpf(x);
#else
    return 1.0f / x;
#endif
}
__device__ __forceinline__ v2f fma2(v2f a, v2f b, v2f c) {   // v_pk_fma_f32 (R2-verified)
#if __has_builtin(__builtin_elementwise_fma)
    return __builtin_elementwise_fma(a, b, c);
#else
    return (v2f){fmaf(a.x, b.x, c.x), fmaf(a.y, b.y, c.y)};
#endif
}

// ---------------------------------------------------------------------------
// Kernel 1: px[b][t][q] = sum_d x[t,b,d]*Wp[q,d] + qp[q]   (unchanged, verified)
// ---------------------------------------------------------------------------
__global__ __launch_bounds__(256) void qlstm_projx(const float* __restrict__ x,
                                                   const float* __restrict__ Wp,
                                                   const float* __restrict__ qp,
                                                   float* __restrict__ px) {
    const int wave = threadIdx.x >> 6;
    const int lane = threadIdx.x & 63;
    const int row  = blockIdx.x * 4 + wave;       // row = t*BATCH + b

    const float4 xv = ((const float4*)(x + (size_t)row * DIN))[lane];
    float acc[8];
#pragma unroll
    for (int Q = 0; Q < 8; ++Q) {
        float4 w = ((const float4*)(Wp + Q * WPLD))[lane];
        acc[Q] = xv.x * w.x + xv.y * w.y + xv.z * w.z + xv.w * w.w;
    }
#pragma unroll
    for (int Q = 0; Q < 8; ++Q) {
        acc[Q] += dppmov<0xB1>(acc[Q]);
        acc[Q] += dppmov<0x4E>(acc[Q]);
        acc[Q] += swz<0x101F>(acc[Q]);
    }
    float p = acc[0];
#pragma unroll
    for (int j = 1; j < 8; ++j) p = ((lane & 7) == j) ? acc[j] : p;
    p += swz<0x201F>(p);
    p += swz<0x401F>(p);
    p += __shfl_xor(p, 32);
    if (lane < 8) {
        const int bb = row & (BATCH - 1);
        const int tt = row >> 7;
        px[(size_t)bb * (T_STEPS * 8) + tt * 8 + lane] = p + qp[lane];
    }
}

// ---------------------------------------------------------------------------
// Kernel 2: recurrence = R12's verified two-phase structure, but TWO batch
// rows per block (512 threads, 8 waves -> 2 waves/SIMD): while one row's
// waves sit in the exposed LDS/barrier/exp latency, the other row's waves
// issue — per-SIMD latency hiding that 1 wave/SIMD cannot do. Per-row logic
// and math are verbatim R12 (arrays indexed by row r). Gates use packed
// v_pk_fma_f32 (fma2, R2-verified) to trim issue.
// ---------------------------------------------------------------------------
__global__ __launch_bounds__(512, 1) void qlstm_seq(const float* __restrict__ hx,
                                                    const float* __restrict__ cx,
                                                    const float* __restrict__ Wp,
                                                    const float* __restrict__ Wg,
                                                    const float* __restrict__ bg,
                                                    const float* __restrict__ px,
                                                    float* __restrict__ out) {
    __shared__ float px_lds[2][(T_STEPS + 1) * 8];   // per-row px (+pad)
    __shared__ float hbuf[2][HID];                   // per-row h (single-buffered)
    __shared__ float cq_lds[2][8];                   // per-row cos values

    const int tid = threadIdx.x;
    const int r   = tid >> 8;      // row within block (0/1)
    const int rt  = tid & 255;     // thread within row
    const int w   = rt >> 6;       // wave-within-row 0..3 -> owns q=2w,2w+1
    const int l   = rt & 63;       // lane
    const int b   = blockIdx.x * 2 + r;
    const int cg  = rt;            // this thread's gate/LSTM column
    const bool lane0 = (l == 0);

    // ---- weight loads (asm: non-rematerializable) ----
    float4 wph0, wph1;             // Wp[2w][256+4l..], Wp[2w+1][256+4l..]
    {
        const float* a0 = Wp + (2 * w) * WPLD + DIN + 4 * l;
        const float* a1 = Wp + (2 * w + 1) * WPLD + DIN + 4 * l;
        ASM_LOAD4(wph0, a0);
        ASM_LOAD4(wph1, a1);
    }
    float4 WG0[4], WG1[4];         // Wg row (G*256+cg), floats 0..7
#pragma unroll
    for (int G = 0; G < 4; ++G) {
        const float* rr = Wg + (size_t)(G * HID + cg) * 8;
        ASM_LOAD4(WG0[G], rr);
        ASM_LOAD4(WG1[G], rr + 4);
    }
    float bgc[4];                  // bg[G*256+cg]
#pragma unroll
    for (int G = 0; G < 4; ++G) {
        const float* a = bg + G * HID + cg;
        ASM_LOAD1(bgc[G], a);
    }

    // preload this row's px (4096 floats = 1024 float4, 4 per row-thread)
    {
        const float4* pg = (const float4*)(px + (size_t)b * (T_STEPS * 8));
        float4* pl = (float4*)&px_lds[r][0];
#pragma unroll
        for (int j = 0; j < 4; ++j) pl[j * 256 + rt] = pg[j * 256 + rt];
    }

    float c = cx[b * HID + cg];
    hbuf[r][rt] = hx[b * HID + rt];

    asm volatile("s_waitcnt vmcnt(0)" ::: "memory");
    __builtin_amdgcn_sched_barrier(0);
    __syncthreads();   // hbuf + px_lds ready (prologue only)

    // repack gate weights to v2f pairs (one-time register moves)
    v2f wg2[4][4];
#pragma unroll
    for (int G = 0; G < 4; ++G) {
        wg2[G][0] = (v2f){WG0[G].x, WG0[G].y};
        wg2[G][1] = (v2f){WG0[G].z, WG0[G].w};
        wg2[G][2] = (v2f){WG1[G].x, WG1[G].y};
        wg2[G][3] = (v2f){WG1[G].z, WG1[G].w};
    }

    // prefetch this wave's px pair for t=0
    float2 pxp = *(const float2*)&px_lds[r][2 * w];

    float* outp = out + (size_t)b * HID + cg;
    float h = 0.f;

    for (int t = 0; t < T_STEPS; ++t) {
        // ---- phase 1: this wave's two q-dots over the full h (R12 verbatim) ----
        const float4 h4 = *(const float4*)&hbuf[r][4 * l];

        float v0 = lane0 ? pxp.x : 0.f;
        v0 = fmaf(h4.x, wph0.x, v0);
        v0 = fmaf(h4.y, wph0.y, v0);
        v0 = fmaf(h4.z, wph0.z, v0);
        v0 = fmaf(h4.w, wph0.w, v0);
        float v1 = lane0 ? pxp.y : 0.f;
        v1 = fmaf(h4.x, wph1.x, v1);
        v1 = fmaf(h4.y, wph1.y, v1);
        v1 = fmaf(h4.z, wph1.z, v1);
        v1 = fmaf(h4.w, wph1.w, v1);

        // verified butterfly allreduce (two interleaved chains)
        v0 += dppmov<0xB1>(v0);   v1 += dppmov<0xB1>(v1);    // xor1
        v0 += dppmov<0x4E>(v0);   v1 += dppmov<0x4E>(v1);    // xor2
        v0 += dppmov<0x124>(v0);  v1 += dppmov<0x124>(v1);   // ror4
        v0 += dppmov<0x128>(v0);  v1 += dppmov<0x128>(v1);   // ror8
        v0 += lane_xor16(v0, l);  v1 += lane_xor16(v1, l);
        v0 += lane_xor32(v0, l);  v1 += lane_xor32(v1, l);

        const float cq0 = __cosf(v0);
        const float cq1 = __cosf(v1);
        if (lane0) {
            *(float2*)&cq_lds[r][2 * w] = make_float2(cq0, cq1);
        }
        STEP_BARRIER();   // bar1: cq visible; separates h-read from h-write

        // ---- phase 2: gates/LSTM for this thread's column ----
        const float4 cqa = *(const float4*)&cq_lds[r][0];
        const float4 cqb = *(const float4*)&cq_lds[r][4];

        // prefetch px pair for t+1 (independent of cq)
        pxp = *(const float2*)&px_lds[r][(t + 1) * 8 + 2 * w];

        const float C0 = cqa.x, C1 = cqa.y, C2 = cqa.z, C3 = cqa.w;
        const float C4 = cqb.x, C5 = cqb.y, C6 = cqb.z, C7 = cqb.w;

        // prefix products: qo[0]=C1..C7, qo[k>=1]=C0..Ck
        const float d01 = C0 * C1, d23 = C2 * C3, d45 = C4 * C5, d67 = C6 * C7;
        const float q1 = d01;
        const float q2 = d01 * C2;
        const float q3 = d01 * d23;
        const float q4 = q3 * C4;
        const float q5 = q3 * d45;
        const float q6 = q5 * C6;
        const float q7 = q5 * d67;
        const float q0 = (C1 * d23) * (d45 * d67);

        const v2f qv[4] = {(v2f){q0, q1}, (v2f){q2, q3}, (v2f){q4, q5}, (v2f){q6, q7}};

        // gates: packed FMA (v_pk_fma_f32), 4 pk-fma + 1 add per gate
        float g[4];
#pragma unroll
        for (int G = 0; G < 4; ++G) {
            v2f acc = (v2f){bgc[G], 0.f};
            acc = fma2(wg2[G][0], qv[0], acc);
            acc = fma2(wg2[G][1], qv[1], acc);
            acc = fma2(wg2[G][2], qv[2], acc);
            acc = fma2(wg2[G][3], qv[3], acc);
            g[G] = acc.x + acc.y;
        }

        // LSTM pointwise, parallel form (inf-safe, no clamp) — as R12
        const float sf = rcp_f(1.f + __expf(-g[0]));
        const float si = rcp_f(1.f + __expf(-g[1]));
        const float so = rcp_f(1.f + __expf(-g[3]));
        const float tg = 1.f - 2.f * rcp_f(__expf(2.f * g[2]) + 1.f);
        const float cn = fmaf(sf, c, si * tg);
        const float th = 1.f - 2.f * rcp_f(__expf(2.f * cn) + 1.f);
        h = so * th;
        c = cn;

        *outp = h;                   // global store; not drained at barriers
        outp += BATCH * HID;

        hbuf[r][cg] = h;             // publish new h
        STEP_BARRIER();              // bar2: h visible; separates cq read/write
    }

    const size_t base = (size_t)T_STEPS * BATCH * HID;
    out[base + b * HID + cg] = h;
    out[base + BATCH * HID + b * HID + cg] = c;
}

extern "C" void kernel_launch(void* const* d_in, const int* in_sizes, int n_in,
                              void* d_out, int out_size, void* d_ws, size_t ws_size,
                              hipStream_t stream) {
    const float* x   = (const float*)d_in[0];   // (512,128,256)
    const float* hx  = (const float*)d_in[1];   // (128,256)
    const float* cx  = (const float*)d_in[2];   // (128,256)
    const float* Wp  = (const float*)d_in[3];   // (8,512)
    const float* qp  = (const float*)d_in[4];   // (8,)
    const float* Wg  = (const float*)d_in[5];   // (1024,8)
    const float* bg  = (const float*)d_in[6];   // (1024,)
    float* out = (float*)d_out;
    float* px  = (float*)d_ws;                  // 128*512*8 floats = 2 MB

    qlstm_projx<<<(T_STEPS * BATCH) / 4, 256, 0, stream>>>(x, Wp, qp, px);
    qlstm_seq<<<BATCH / 2, 512, 0, stream>>>(hx, cx, Wp, Wg, bg, px, out);
}

// Round 19
// 263.149 us; speedup vs baseline: 1.5331x; 1.3858x over previous
//
#include <hip/hip_runtime.h>

#ifndef __has_builtin
#define __has_builtin(x) 0
#endif

#define T_STEPS 512
#define BATCH   128
#define DIN     256
#define HID     256
#define WPLD    (DIN + HID)   // 512

typedef float v2f __attribute__((ext_vector_type(2)));

// Volatile asm loads: results are NOT rematerializable (cheap insurance).
#define ASM_LOAD4(dst, ptr) \
    asm volatile("global_load_dwordx4 %0, %1, off" : "=v"(dst) : "v"(ptr))
#define ASM_LOAD1(dst, ptr) \
    asm volatile("global_load_dword %0, %1, off" : "=v"(dst) : "v"(ptr))

// Barrier WITHOUT vmcnt drain (verified R11/R12): waits only LDS ops.
#define STEP_BARRIER() do {                                   \
    asm volatile("s_waitcnt lgkmcnt(0)" ::: "memory");        \
    __builtin_amdgcn_s_barrier();                             \
    __builtin_amdgcn_sched_barrier(0);                        \
} while (0)

// ---------------- cross-lane helpers (verified in passing runs) ----------------
template<int CTRL>
__device__ __forceinline__ float dppmov(float x) {
    // 0xB1=quad xor1, 0x4E=quad xor2, 0x124=row_ror:4, 0x128=row_ror:8
    return __int_as_float(__builtin_amdgcn_update_dpp(0, __float_as_int(x), CTRL, 0xF, 0xF, true));
}
template<int PAT>
__device__ __forceinline__ float swz(float x) {
    return __int_as_float(__builtin_amdgcn_ds_swizzle(__float_as_int(x), PAT));
}
__device__ __forceinline__ float lane_xor16(float v, int l) {
#if __has_builtin(__builtin_amdgcn_permlane16_swap)
    auto r = __builtin_amdgcn_permlane16_swap(__float_as_uint(v), __float_as_uint(v), false, false);
    return __uint_as_float((l & 16) ? r[0] : r[1]);
#else
    return swz<0x401F>(v);
#endif
}
__device__ __forceinline__ float lane_xor32(float v, int l) {
#if __has_builtin(__builtin_amdgcn_permlane32_swap)
    auto r = __builtin_amdgcn_permlane32_swap(__float_as_uint(v), __float_as_uint(v), false, false);
    return __uint_as_float((l & 32) ? r[0] : r[1]);
#else
    return __shfl_xor(v, 32);
#endif
}
__device__ __forceinline__ float rcp_f(float x) {
#if __has_builtin(__builtin_amdgcn_rcpf)
    return __builtin_amdgcn_rcpf(x);
#else
    return 1.0f / x;
#endif
}
__device__ __forceinline__ v2f fma2(v2f a, v2f b, v2f c) {   // v_pk_fma_f32 (R18-verified)
#if __has_builtin(__builtin_elementwise_fma)
    return __builtin_elementwise_fma(a, b, c);
#else
    return (v2f){fmaf(a.x, b.x, c.x), fmaf(a.y, b.y, c.y)};
#endif
}

// ---------------------------------------------------------------------------
// Kernel 1: px[b][t][q] = sum_d x[t,b,d]*Wp[q,d] + qp[q]   (unchanged, verified)
// ---------------------------------------------------------------------------
__global__ __launch_bounds__(256) void qlstm_projx(const float* __restrict__ x,
                                                   const float* __restrict__ Wp,
                                                   const float* __restrict__ qp,
                                                   float* __restrict__ px) {
    const int wave = threadIdx.x >> 6;
    const int lane = threadIdx.x & 63;
    const int row  = blockIdx.x * 4 + wave;       // row = t*BATCH + b

    const float4 xv = ((const float4*)(x + (size_t)row * DIN))[lane];
    float acc[8];
#pragma unroll
    for (int Q = 0; Q < 8; ++Q) {
        float4 w = ((const float4*)(Wp + Q * WPLD))[lane];
        acc[Q] = xv.x * w.x + xv.y * w.y + xv.z * w.z + xv.w * w.w;
    }
#pragma unroll
    for (int Q = 0; Q < 8; ++Q) {
        acc[Q] += dppmov<0xB1>(acc[Q]);
        acc[Q] += dppmov<0x4E>(acc[Q]);
        acc[Q] += swz<0x101F>(acc[Q]);
    }
    float p = acc[0];
#pragma unroll
    for (int j = 1; j < 8; ++j) p = ((lane & 7) == j) ? acc[j] : p;
    p += swz<0x201F>(p);
    p += swz<0x401F>(p);
    p += __shfl_xor(p, 32);
    if (lane < 8) {
        const int bb = row & (BATCH - 1);
        const int tt = row >> 7;
        px[(size_t)bb * (T_STEPS * 8) + tt * 8 + lane] = p + qp[lane];
    }
}

// ---------------------------------------------------------------------------
// Kernel 2: recurrence = R12's verified two-phase structure (262 us), with
// issue trims only: pk-fma proj dot, px added after the reduce (uniform add,
// no cndmask on chain head), pk-fma gates (R18-verified fma2). One row per
// block, 4 waves, wave w owns q=2w,2w+1; two STEP_BARRIERs per step.
// ---------------------------------------------------------------------------
__global__ __launch_bounds__(256, 1) void qlstm_seq(const float* __restrict__ hx,
                                                    const float* __restrict__ cx,
                                                    const float* __restrict__ Wp,
                                                    const float* __restrict__ Wg,
                                                    const float* __restrict__ bg,
                                                    const float* __restrict__ px,
                                                    float* __restrict__ out) {
    __shared__ float px_lds[(T_STEPS + 1) * 8];   // +8 pad for prefetch overrun
    __shared__ float hbuf[HID];                   // single-buffered h
    __shared__ float cq_lds[8];                   // single-buffered cos values

    const int tid = threadIdx.x;
    const int w   = tid >> 6;     // wave id 0..3 -> owns q=2w,2w+1
    const int l   = tid & 63;     // lane
    const int b   = blockIdx.x;
    const int cg  = tid;          // this thread's gate/LSTM column

    // ---- weight loads (asm: non-rematerializable) ----
    float4 wph0, wph1;            // Wp[2w][256+4l..], Wp[2w+1][256+4l..]
    {
        const float* a0 = Wp + (2 * w) * WPLD + DIN + 4 * l;
        const float* a1 = Wp + (2 * w + 1) * WPLD + DIN + 4 * l;
        ASM_LOAD4(wph0, a0);
        ASM_LOAD4(wph1, a1);
    }
    float4 WG0[4], WG1[4];        // Wg row (G*256+cg), floats 0..7
#pragma unroll
    for (int G = 0; G < 4; ++G) {
        const float* r = Wg + (size_t)(G * HID + cg) * 8;
        ASM_LOAD4(WG0[G], r);
        ASM_LOAD4(WG1[G], r + 4);
    }
    float bgc[4];                 // bg[G*256+cg]
#pragma unroll
    for (int G = 0; G < 4; ++G) {
        const float* a = bg + G * HID + cg;
        ASM_LOAD1(bgc[G], a);
    }

    // preload all px for this b (4096 floats = 1024 float4, 4 per thread)
    {
        const float4* pg = (const float4*)(px + (size_t)b * (T_STEPS * 8));
        float4* pl = (float4*)px_lds;
#pragma unroll
        for (int j = 0; j < 4; ++j) pl[j * 256 + tid] = pg[j * 256 + tid];
    }

    float c = cx[b * HID + cg];
    hbuf[tid] = hx[b * HID + tid];

    asm volatile("s_waitcnt vmcnt(0)" ::: "memory");
    __builtin_amdgcn_sched_barrier(0);
    __syncthreads();   // hbuf + px_lds ready (prologue only)

    // repack proj weights to v2f (one-time register moves)
    const v2f wA0 = (v2f){wph0.x, wph0.y}, wB0 = (v2f){wph0.z, wph0.w};
    const v2f wA1 = (v2f){wph1.x, wph1.y}, wB1 = (v2f){wph1.z, wph1.w};
    // repack gate weights to v2f pairs
    v2f wg2[4][4];
#pragma unroll
    for (int G = 0; G < 4; ++G) {
        wg2[G][0] = (v2f){WG0[G].x, WG0[G].y};
        wg2[G][1] = (v2f){WG0[G].z, WG0[G].w};
        wg2[G][2] = (v2f){WG1[G].x, WG1[G].y};
        wg2[G][3] = (v2f){WG1[G].z, WG1[G].w};
    }

    // prefetch this wave's px pair for t=0
    float2 pxp = *(const float2*)&px_lds[2 * w];

    float* outp = out + (size_t)b * HID + cg;
    float h = 0.f;

    for (int t = 0; t < T_STEPS; ++t) {
        // ---- phase 1: this wave's two q-dots over the full h ----
        const float4 h4 = *(const float4*)&hbuf[4 * l];
        const v2f hA = (v2f){h4.x, h4.y}, hB = (v2f){h4.z, h4.w};

        v2f a0 = hA * wA0;  a0 = fma2(hB, wB0, a0);
        v2f a1 = hA * wA1;  a1 = fma2(hB, wB1, a1);
        float v0 = a0.x + a0.y;
        float v1 = a1.x + a1.y;

        // verified butterfly allreduce (two interleaved chains)
        v0 += dppmov<0xB1>(v0);   v1 += dppmov<0xB1>(v1);    // xor1
        v0 += dppmov<0x4E>(v0);   v1 += dppmov<0x4E>(v1);    // xor2
        v0 += dppmov<0x124>(v0);  v1 += dppmov<0x124>(v1);   // ror4
        v0 += dppmov<0x128>(v0);  v1 += dppmov<0x128>(v1);   // ror8
        v0 += lane_xor16(v0, l);  v1 += lane_xor16(v1, l);
        v0 += lane_xor32(v0, l);  v1 += lane_xor32(v1, l);

        // px folded AFTER the reduce: uniform add, off the chain head
        const float cq0 = __cosf(v0 + pxp.x);
        const float cq1 = __cosf(v1 + pxp.y);
        if (l == 0) {
            *(float2*)&cq_lds[2 * w] = make_float2(cq0, cq1);
        }
        STEP_BARRIER();   // bar1: cq visible; separates h-read from h-write

        // ---- phase 2: gates/LSTM for this thread's column ----
        const float4 cqa = *(const float4*)&cq_lds[0];
        const float4 cqb = *(const float4*)&cq_lds[4];

        // prefetch px pair for t+1 (independent of cq)
        pxp = *(const float2*)&px_lds[(t + 1) * 8 + 2 * w];

        const float C0 = cqa.x, C1 = cqa.y, C2 = cqa.z, C3 = cqa.w;
        const float C4 = cqb.x, C5 = cqb.y, C6 = cqb.z, C7 = cqb.w;

        // prefix products: qo[0]=C1..C7, qo[k>=1]=C0..Ck
        const float d01 = C0 * C1, d23 = C2 * C3, d45 = C4 * C5, d67 = C6 * C7;
        const float q1 = d01;
        const float q2 = d01 * C2;
        const float q3 = d01 * d23;
        const float q4 = q3 * C4;
        const float q5 = q3 * d45;
        const float q6 = q5 * C6;
        const float q7 = q5 * d67;
        const float q0 = (C1 * d23) * (d45 * d67);

        const v2f qv[4] = {(v2f){q0, q1}, (v2f){q2, q3}, (v2f){q4, q5}, (v2f){q6, q7}};

        // gates: packed FMA (v_pk_fma_f32), 4 pk-fma + 1 add per gate
        float g[4];
#pragma unroll
        for (int G = 0; G < 4; ++G) {
            v2f acc = (v2f){bgc[G], 0.f};
            acc = fma2(wg2[G][0], qv[0], acc);
            acc = fma2(wg2[G][1], qv[1], acc);
            acc = fma2(wg2[G][2], qv[2], acc);
            acc = fma2(wg2[G][3], qv[3], acc);
            g[G] = acc.x + acc.y;
        }

        // LSTM pointwise, parallel form (inf-safe, no clamp) — as R12
        const float sf = rcp_f(1.f + __expf(-g[0]));
        const float si = rcp_f(1.f + __expf(-g[1]));
        const float so = rcp_f(1.f + __expf(-g[3]));
        const float tg = 1.f - 2.f * rcp_f(__expf(2.f * g[2]) + 1.f);
        const float cn = fmaf(sf, c, si * tg);
        const float th = 1.f - 2.f * rcp_f(__expf(2.f * cn) + 1.f);
        h = so * th;
        c = cn;

        *outp = h;                   // global store; not drained at barriers
        outp += BATCH * HID;

        hbuf[cg] = h;                // publish new h
        STEP_BARRIER();              // bar2: h visible; separates cq read/write
    }

    const size_t base = (size_t)T_STEPS * BATCH * HID;
    out[base + b * HID + cg] = h;
    out[base + BATCH * HID + b * HID + cg] = c;
}

extern "C" void kernel_launch(void* const* d_in, const int* in_sizes, int n_in,
                              void* d_out, int out_size, void* d_ws, size_t ws_size,
                              hipStream_t stream) {
    const float* x   = (const float*)d_in[0];   // (512,128,256)
    const float* hx  = (const float*)d_in[1];   // (128,256)
    const float* cx  = (const float*)d_in[2];   // (128,256)
    const float* Wp  = (const float*)d_in[3];   // (8,512)
    const float* qp  = (const float*)d_in[4];   // (8,)
    const float* Wg  = (const float*)d_in[5];   // (1024,8)
    const float* bg  = (const float*)d_in[6];   // (1024,)
    float* out = (float*)d_out;
    float* px  = (float*)d_ws;                  // 128*512*8 floats = 2 MB

    qlstm_projx<<<(T_STEPS * BATCH) / 4, 256, 0, stream>>>(x, Wp, qp, px);
    qlstm_seq<<<BATCH, 256, 0, stream>>>(hx, cx, Wp, Wg, bg, px, out);
}